// Round 1
// baseline (436.636 us; speedup 1.0000x reference)
//
#include <hip/hip_runtime.h>

#define NEG 0.01f

// ---------------- CSR build ----------------

__global__ void count_kernel(const int* __restrict__ dst, int* __restrict__ cnt, int E) {
  int e = blockIdx.x * blockDim.x + threadIdx.x;
  if (e < E) atomicAdd(&cnt[dst[e]], 1);
}

__global__ void dinv_kernel(const int* __restrict__ cnt, float* __restrict__ dinv, int n) {
  int i = blockIdx.x * blockDim.x + threadIdx.x;
  if (i < n) dinv[i] = rsqrtf((float)cnt[i] + 1.0f);  // +1 self-loop; deg>=1 always
}

// single-block exclusive scan over n counts -> row_ptr[n+1], nxt[n]
__global__ void scan_kernel(const int* __restrict__ cnt, int* __restrict__ row_ptr,
                            int* __restrict__ nxt, int n) {
  __shared__ int tsum[1024];
  int tid = threadIdx.x;
  int chunk = (n + 1023) >> 10;
  int start = tid * chunk;
  int end = min(start + chunk, n);
  int sum = 0;
  for (int i = start; i < end; ++i) sum += cnt[i];
  tsum[tid] = sum;
  __syncthreads();
  for (int off = 1; off < 1024; off <<= 1) {
    int v = (tid >= off) ? tsum[tid - off] : 0;
    __syncthreads();
    tsum[tid] += v;
    __syncthreads();
  }
  int running = tsum[tid] - sum;  // exclusive prefix
  for (int i = start; i < end; ++i) {
    row_ptr[i] = running;
    nxt[i] = running;
    running += cnt[i];
  }
  if (start < n && end == n) row_ptr[n] = running;
}

__global__ void fill_kernel(const int* __restrict__ src, const int* __restrict__ dst,
                            const float* __restrict__ dinv, int* __restrict__ nxt,
                            int* __restrict__ col, float* __restrict__ wcsr, int E) {
  int e = blockIdx.x * blockDim.x + threadIdx.x;
  if (e < E) {
    int d = dst[e], s = src[e];
    int pos = atomicAdd(&nxt[d], 1);
    col[pos] = s;
    wcsr[pos] = dinv[s] * dinv[d];
  }
}

// ---------------- GEMMs (f32 vector ALU; no fp32 MFMA on CDNA4) ----------------

// h[n,128] = x[n,64] @ W[64,128]; 2 nodes per iter, W in LDS (32 KB)
__global__ __launch_bounds__(256) void gemm1_kernel(const float* __restrict__ x,
                                                    const float* __restrict__ W,
                                                    float* __restrict__ h, int n) {
  __shared__ float sW[64 * 128];
  __shared__ float sx[2][64];
  for (int idx = threadIdx.x; idx < 64 * 128; idx += 256) sW[idx] = W[idx];
  int npairs = (n + 1) >> 1;
  for (int p = blockIdx.x; p < npairs; p += gridDim.x) {
    int node0 = p << 1;
    __syncthreads();  // protect sx reuse (and sW on first iter before second sync)
    if (threadIdx.x < 128) {
      int node = node0 + (threadIdx.x >> 6);
      int k = threadIdx.x & 63;
      sx[threadIdx.x >> 6][k] = (node < n) ? x[node * 64 + k] : 0.f;
    }
    __syncthreads();
    int local = threadIdx.x >> 7;     // 0..1
    int j = threadIdx.x & 127;        // output feature
    int node = node0 + local;
    if (node < n) {
      float acc = 0.f;
#pragma unroll
      for (int k = 0; k < 64; ++k) acc = fmaf(sx[local][k], sW[k * 128 + j], acc);
      h[node * 128 + j] = acc;
    }
  }
}

// h[n,64] = y[n,128] @ W[128,64]; 4 nodes per iter, W in LDS (32 KB)
__global__ __launch_bounds__(256) void gemm2_kernel(const float* __restrict__ y,
                                                    const float* __restrict__ W,
                                                    float* __restrict__ h, int n) {
  __shared__ float sW[128 * 64];
  __shared__ float sy[4][128];
  for (int idx = threadIdx.x; idx < 128 * 64; idx += 256) sW[idx] = W[idx];
  int nquads = (n + 3) >> 2;
  for (int q = blockIdx.x; q < nquads; q += gridDim.x) {
    int node0 = q << 2;
    __syncthreads();
    for (int t = threadIdx.x; t < 512; t += 256) {
      int node = node0 + (t >> 7);
      int k = t & 127;
      sy[t >> 7][k] = (node < n) ? y[node * 128 + k] : 0.f;
    }
    __syncthreads();
    int local = threadIdx.x >> 6;     // 0..3
    int j = threadIdx.x & 63;
    int node = node0 + local;
    if (node < n) {
      float acc = 0.f;
#pragma unroll
      for (int k = 0; k < 128; ++k) acc = fmaf(sy[local][k], sW[k * 64 + j], acc);
      h[node * 64 + j] = acc;
    }
  }
}

// ---------------- Aggregation (CSR, deterministic per-row loop) ----------------

// y1[i,:] = leaky_relu( sum_{s in N(i)} w*h1[s,:] + dinv_i^2*h1[i,:] + b )
__global__ void agg1_kernel(const float* __restrict__ h1, const float* __restrict__ dinv,
                            const int* __restrict__ row_ptr, const int* __restrict__ col,
                            const float* __restrict__ wcsr, const float* __restrict__ b,
                            float* __restrict__ y1, int n) {
  int j = threadIdx.x;  // 128
  for (int i = blockIdx.x; i < n; i += gridDim.x) {
    float di = dinv[i];
    float acc = h1[(size_t)i * 128 + j] * (di * di);
    int e0 = row_ptr[i], e1 = row_ptr[i + 1];
    for (int e = e0; e < e1; ++e) {
      acc = fmaf(h1[(size_t)col[e] * 128 + j], wcsr[e], acc);
    }
    float v = acc + b[j];
    y1[(size_t)i * 128 + j] = (v >= 0.f) ? v : NEG * v;
  }
}

// out[i,:] = x[i,:] + sum w*h2[s,:] + dinv_i^2*h2[i,:] + b
__global__ void agg2_kernel(const float* __restrict__ h2, const float* __restrict__ dinv,
                            const int* __restrict__ row_ptr, const int* __restrict__ col,
                            const float* __restrict__ wcsr, const float* __restrict__ b,
                            const float* __restrict__ x, float* __restrict__ out, int n) {
  int j = threadIdx.x;  // 64
  for (int i = blockIdx.x; i < n; i += gridDim.x) {
    float di = dinv[i];
    float acc = h2[(size_t)i * 64 + j] * (di * di);
    int e0 = row_ptr[i], e1 = row_ptr[i + 1];
    for (int e = e0; e < e1; ++e) {
      acc = fmaf(h2[(size_t)col[e] * 64 + j], wcsr[e], acc);
    }
    out[(size_t)i * 64 + j] = x[(size_t)i * 64 + j] + acc + b[j];
  }
}

// ---------------- launch ----------------

extern "C" void kernel_launch(void* const* d_in, const int* in_sizes, int n_in,
                              void* d_out, int out_size, void* d_ws, size_t ws_size,
                              hipStream_t stream) {
  const int n = in_sizes[0] / 64;   // 50000
  const int E = in_sizes[5] / 2;    // 800000

  const float* x  = (const float*)d_in[0];
  const float* W1 = (const float*)d_in[1];
  const float* b1 = (const float*)d_in[2];
  const float* W2 = (const float*)d_in[3];
  const float* b2 = (const float*)d_in[4];
  const int* edge = (const int*)d_in[5];
  const int* esrc = edge;       // edge_index[0]
  const int* edst = edge + E;   // edge_index[1]

  char* ws = (char*)d_ws;
  size_t o = 0;
  auto take = [&](size_t bytes) -> void* {
    void* p = ws + o;
    o += (bytes + 255) & ~(size_t)255;
    return p;
  };
  int*   cnt     = (int*)take((size_t)n * 4);
  int*   row_ptr = (int*)take((size_t)(n + 1) * 4);
  int*   nxt     = (int*)take((size_t)n * 4);
  float* dinv    = (float*)take((size_t)n * 4);
  int*   col     = (int*)take((size_t)E * 4);
  float* wcsr    = (float*)take((size_t)E * 4);
  float* h1      = (float*)take((size_t)n * 128 * 4);
  float* y1      = (float*)take((size_t)n * 128 * 4);
  float* h2      = h1;  // h1 dead after agg1; reuse for layer-2 GEMM output

  hipMemsetAsync(cnt, 0, (size_t)n * 4, stream);

  int eb = (E + 255) / 256;
  int nb = (n + 255) / 256;

  count_kernel<<<eb, 256, 0, stream>>>(edst, cnt, E);
  dinv_kernel<<<nb, 256, 0, stream>>>(cnt, dinv, n);
  scan_kernel<<<1, 1024, 0, stream>>>(cnt, row_ptr, nxt, n);
  fill_kernel<<<eb, 256, 0, stream>>>(esrc, edst, dinv, nxt, col, wcsr, E);

  gemm1_kernel<<<512, 256, 0, stream>>>(x, W1, h1, n);
  agg1_kernel<<<n, 128, 0, stream>>>(h1, dinv, row_ptr, col, wcsr, b1, y1, n);
  gemm2_kernel<<<512, 256, 0, stream>>>(y1, W2, h2, n);
  agg2_kernel<<<n, 64, 0, stream>>>(h2, dinv, row_ptr, col, wcsr, b2, x,
                                    (float*)d_out, n);
}